// Round 12
// baseline (533.964 us; speedup 1.0000x reference)
//
#include <hip/hip_runtime.h>
#include <math.h>

#define NPTS 1024
#define BB 2
#define KNN 20
#define ROWS 2048
#define CATC 960
#define TT 3
#define IDXS 32
typedef unsigned long long ull;
typedef __attribute__((ext_vector_type(8))) short bf16x8;
typedef __attribute__((ext_vector_type(4))) float f32x4;

__device__ __forceinline__ float lrelu_f(float x){ return x >= 0.f ? x : 0.2f*x; }
__device__ __forceinline__ unsigned short f2bf(float f){
  unsigned u = __float_as_uint(f);
  return (unsigned short)((u + 0x7FFFu + ((u >> 16) & 1u)) >> 16);
}
__device__ __forceinline__ float bf2f(unsigned short h){ return __uint_as_float(((unsigned)h) << 16); }

__device__ __forceinline__ void stg_u32(unsigned* p, unsigned v){ __hip_atomic_store(p, v, __ATOMIC_RELAXED, __HIP_MEMORY_SCOPE_AGENT); }
__device__ __forceinline__ void stg_f64(double* p, double v){ __hip_atomic_store(p, v, __ATOMIC_RELAXED, __HIP_MEMORY_SCOPE_AGENT); }
__device__ __forceinline__ unsigned ldg_u32(const unsigned* p){ return __hip_atomic_load(p, __ATOMIC_RELAXED, __HIP_MEMORY_SCOPE_AGENT); }
__device__ __forceinline__ double ldg_f64(const double* p){ return __hip_atomic_load(p, __ATOMIC_RELAXED, __HIP_MEMORY_SCOPE_AGENT); }

// ===================== MFMA bf16 3-split conv GEMM (LDS-free, 64x64 tile) =====================
__device__ __forceinline__ void mfma_dev(const short* __restrict__ A, int lda,
    const short* __restrict__ B3, size_t sStride, int ldb,
    float* __restrict__ C, int ldc, int K, int bm, int bn, int tid)
{
  const int wave = tid >> 6, lane = tid & 63;
  const int wm = (wave >> 1) << 5, wn = (wave & 1) << 5;
  const int rr = lane & 15, kq = (lane >> 4) << 3;
  f32x4 acc[2][2] = {};
  const short* Ap = A + (size_t)(bm + wm + rr)*lda + kq;
  const short* Bp = B3 + (size_t)(bn + wn + rr)*ldb + kq;
  for (int k0 = 0; k0 < K; k0 += 32) {
    bf16x8 a0 = *(const bf16x8*)(Ap + k0);
    bf16x8 a1 = *(const bf16x8*)(Ap + (size_t)16*lda + k0);
#pragma unroll
    for (int s = 0; s < 3; ++s) {
      bf16x8 b0 = *(const bf16x8*)(Bp + (size_t)s*sStride + k0);
      bf16x8 b1 = *(const bf16x8*)(Bp + (size_t)s*sStride + (size_t)16*ldb + k0);
      acc[0][0] = __builtin_amdgcn_mfma_f32_16x16x32_bf16(a0, b0, acc[0][0], 0, 0, 0);
      acc[0][1] = __builtin_amdgcn_mfma_f32_16x16x32_bf16(a0, b1, acc[0][1], 0, 0, 0);
      acc[1][0] = __builtin_amdgcn_mfma_f32_16x16x32_bf16(a1, b0, acc[1][0], 0, 0, 0);
      acc[1][1] = __builtin_amdgcn_mfma_f32_16x16x32_bf16(a1, b1, acc[1][1], 0, 0, 0);
    }
  }
  const int drb = (lane >> 4) << 2;
#pragma unroll
  for (int i = 0; i < 2; ++i)
#pragma unroll
    for (int j = 0; j < 2; ++j)
#pragma unroll
      for (int t = 0; t < 4; ++t)
        C[(size_t)(bm + wm + i*16 + drb + t)*ldc + bn + wn + j*16 + rr] = acc[i][j][t];
}

// ===================== agg MFMA 32x32 tile (1024 blocks): fused column stats =====================
// Each wave owns an independent 16x16 x K=960 chain -> 4x block count vs 64x32, 50% occupancy.
__device__ __forceinline__ void agg_tile32(const short* __restrict__ scat, const short* __restrict__ WmH,
    double* __restrict__ Sa1, double* __restrict__ Sa2, unsigned* __restrict__ mxe,
    int tm, int tn, int tid)
{
  const int wave = tid >> 6, lane = tid & 63;
  const int wm = (wave >> 1) << 4;   // 0/16
  const int wn = (wave & 1) << 4;    // 0/16
  const int rr = lane & 15, kq = (lane >> 4) << 3;
  const int bm = tm*32, bn = tn*32;
  f32x4 acc = {};
  const short* Ap = scat + (size_t)(bm + wm + rr)*CATC + kq;
  const short* Bp = WmH + (size_t)(bn + wn + rr)*960 + kq;
  for (int k0 = 0; k0 < 960; k0 += 32){
    bf16x8 a0 = *(const bf16x8*)(Ap + k0);
#pragma unroll
    for (int s = 0; s < 3; ++s){
      bf16x8 b0 = *(const bf16x8*)(Bp + (size_t)s*491520 + k0);
      acc = __builtin_amdgcn_mfma_f32_16x16x32_bf16(a0, b0, acc, 0, 0, 0);
    }
  }
  double ds = 0.0, dq = 0.0; float mx = -INFINITY;
#pragma unroll
  for (int t = 0; t < 4; ++t){
    float v = acc[t];
    ds += (double)v; dq += (double)v*(double)v; mx = fmaxf(mx, v);
  }
#pragma unroll
  for (int off = 16; off < 64; off <<= 1){
    ds += __shfl_xor(ds, off);
    dq += __shfl_xor(dq, off);
    float o = __shfl_xor(mx, off); mx = fmaxf(mx, o);
  }
  if (lane < 16){
    int col = bn + wn + lane;
    atomicAdd(&Sa1[col], ds);
    atomicAdd(&Sa2[col], dq);
    unsigned u = __float_as_uint(mx);
    u = (u & 0x80000000u) ? ~u : (u | 0x80000000u);
    atomicMax(&mxe[(tm >> 5)*512 + col], u);
  }
}

// ===================== wave-level popcount KNN =====================
template<int W>
__device__ __forceinline__ void knn_wave(const ull* __restrict__ pk, int* __restrict__ idx,
                                         int row, int lane)
{
  const int n = row & (NPTS-1), b = row >> 10;
  const ull* pb = pk + (size_t)b*NPTS*W;
  ull cw[W]; int pn = 0;
#pragma unroll
  for (int w=0; w<W; ++w){ cw[w] = pb[(size_t)n*W + w]; pn += __popcll(cw[w]); }
  unsigned keys[16];
#pragma unroll 4
  for (int i=0;i<16;++i){
    int m = lane + (i<<6);
    int inner=0, pm=0;
#pragma unroll
    for (int w=0;w<W;++w){
      ull rm = pb[(size_t)m*W + w];
      inner += __popcll(rm & cw[w]);
      pm    += __popcll(rm);
    }
    int d = 2*inner - pn - pm;
    keys[i] = ((unsigned)(d+1024)<<11) | (unsigned)(NPTS-1-m);
  }
  unsigned lmax = keys[0];
#pragma unroll
  for (int i=1;i<16;++i) lmax = keys[i]>lmax ? keys[i] : lmax;
  unsigned mywin = 0;
  for (int s=0;s<KNN;++s){
    unsigned v = lmax;
#pragma unroll
    for (int off=1; off<64; off<<=1){ unsigned o = __shfl_xor(v, off, 64); if (o>v) v=o; }
    if (lane == s) mywin = (unsigned)(NPTS-1) - (v & 0x7FFu);
    if (lmax == v){
#pragma unroll
      for (int i=0;i<16;++i) if (keys[i]==v) keys[i]=0u;
      lmax = keys[0];
#pragma unroll
      for (int i=1;i<16;++i) lmax = keys[i]>lmax ? keys[i] : lmax;
    }
  }
  if (lane < KNN) idx[(size_t)row*IDXS + lane] = (int)mywin;
}

// ===================== layer-0 KNN (fp32, exact ref op order) =====================
__device__ __forceinline__ void knn0_wave(const float* __restrict__ x, int* __restrict__ idx,
                                          int row, int lane)
{
  const int n = row & (NPTS-1), b = row >> 10;
  const float* xb = x + (size_t)b*3*NPTS;
  float fn0 = xb[n], fn1 = xb[NPTS+n], fn2 = xb[2*NPTS+n];
  float x2n = __fadd_rn(__fadd_rn(__fmul_rn(fn0,fn0), __fmul_rn(fn1,fn1)), __fmul_rn(fn2,fn2));
  ull keys[16];
#pragma unroll 4
  for (int i=0;i<16;++i){
    int m = lane + (i<<6);
    float a0 = xb[m], a1 = xb[NPTS+m], a2 = xb[2*NPTS+m];
    float x2m = __fadd_rn(__fadd_rn(__fmul_rn(a0,a0), __fmul_rn(a1,a1)), __fmul_rn(a2,a2));
    float inner = __fadd_rn(__fadd_rn(__fmul_rn(fn0,a0), __fmul_rn(fn1,a1)), __fmul_rn(fn2,a2));
    float v = __fsub_rn(__fsub_rn(__fmul_rn(2.f,inner), x2n), x2m);
    unsigned u = __float_as_uint(v);
    u = (u & 0x80000000u) ? ~u : (u | 0x80000000u);
    keys[i] = ((ull)u << 32) | (unsigned)(NPTS-1-m);
  }
  ull lmax = keys[0];
#pragma unroll
  for (int i=1;i<16;++i) lmax = keys[i]>lmax ? keys[i] : lmax;
  unsigned mywin = 0;
  for (int s=0;s<KNN;++s){
    ull v = lmax;
#pragma unroll
    for (int off=1; off<64; off<<=1){ ull o = __shfl_xor(v, off, 64); if (o>v) v=o; }
    if (lane == s) mywin = (unsigned)(NPTS-1) - (unsigned)(v & 0xFFFFFFFFull);
    if (lmax == v){
#pragma unroll
      for (int i=0;i<16;++i) if (keys[i]==v) keys[i]=0ull;
      lmax = keys[0];
#pragma unroll
      for (int i=1;i<16;++i) lmax = keys[i]>lmax ? keys[i] : lmax;
    }
  }
  if (lane < KNN) idx[(size_t)row*IDXS + lane] = (int)mywin;
}

// ===================== conv0 (K=3, fp32) =====================
__device__ __forceinline__ void conv0_dev(const float* __restrict__ x, const float* __restrict__ W0,
    float* __restrict__ AB0, int tile, int tid, float* sm)
{
  float (*As)[64] = (float(*)[64])sm;
  float (*Bs)[64] = (float(*)[64])(sm + 3*64);
  int bm = (tile >> 1) * 64, bn = (tile & 1) * 64;
  int b = bm >> 10, n0 = bm & (NPTS-1);
  if (tid < 192){ int k = tid >> 6, r = tid & 63; As[k][r] = x[(size_t)b*3072 + k*NPTS + n0 + r]; }
  if (tid >= 64){
    int k = (tid - 64) >> 6, c = (tid - 64) & 63; int row = bn + c;
    Bs[k][c] = (row < 64) ? __fadd_rn(W0[(size_t)row*6+k], W0[(size_t)row*6+3+k])
                          : W0[(size_t)(row-64)*6+k];
  }
  __syncthreads();
  const int tx = tid & 15, ty = tid >> 4;
  float acc[4][4] = {};
#pragma unroll
  for (int kk = 0; kk < 3; ++kk){
    float ar[4], br[4];
#pragma unroll
    for (int i=0;i<4;++i) ar[i] = As[kk][ty*4+i];
#pragma unroll
    for (int j=0;j<4;++j) br[j] = Bs[kk][tx*4+j];
#pragma unroll
    for (int i=0;i<4;++i)
#pragma unroll
      for (int j=0;j<4;++j) acc[i][j] = fmaf(ar[i], br[j], acc[i][j]);
  }
#pragma unroll
  for (int i=0;i<4;++i)
#pragma unroll
    for (int j=0;j<4;++j)
      AB0[(size_t)(bm+ty*4+i)*128 + bn+tx*4+j] = acc[i][j];
  __syncthreads();
}

// ===================== weight split (3x bf16) =====================
__device__ __forceinline__ void wsplit_store(float w, short* dst, size_t NK, size_t e){
  unsigned short h1 = f2bf(w); float f1 = bf2f(h1);
  float r1 = w - f1;
  unsigned short h2 = f2bf(r1); float f2v = bf2f(h2);
  unsigned short h3 = f2bf(r1 - f2v);
  dst[e] = (short)h1; dst[NK + e] = (short)h2; dst[2*NK + e] = (short)h3;
}
__device__ __forceinline__ void wcatsplit(const float* __restrict__ W, short* __restrict__ dst,
                                          int O, int C, size_t e){
  int rr = (int)(e / C), cc = (int)(e - (size_t)rr*C);
  float w = (rr < O) ? __fadd_rn(W[(size_t)rr*2*C + cc], W[(size_t)rr*2*C + C + cc])
                     : W[(size_t)(rr-O)*2*C + cc];
  wsplit_store(w, dst, (size_t)2*O*C, e);
}

// ===================== LIF =====================
__device__ __forceinline__ float lif_step(float h, int o, size_t i, int init,
    double s1v, double s2v,
    const float* gv, const float* bv,
    const float* pmd, const float* pta, const float* prd, const float* ptb,
    float* sM, float* sT, float* sR)
{
  double cnt = (double)ROWS * (double)KNN;
  double mu = s1v / cnt;
  double vv = s2v / cnt - mu*mu;
  float mean = (float)mu;
  float inv  = 1.f / sqrtf((float)vv + 1e-5f);
  h = ((h - mean) * inv) * gv[o] + bv[o];
  h = lrelu_f(h);
  float md = fminf(fmaxf(pmd[o], 0.1f), 0.99f);
  float ta = fminf(fmaxf(pta[o], 0.001f), 0.1f);
  float rd = fminf(fmaxf(prd[o], 0.1f), 0.95f);
  float tb = ptb[o];
  float M, T, R;
  if (init) { M = 0.f; T = tb; R = 0.f; }
  else      { M = sM[i]; T = sT[i]; R = sR[i]; }
  float xv = (R <= 0.f) ? h : 0.f;
  M = M * md * (1.f - R) + xv;
  float sp = (M - T > 0.f) ? 1.f : 0.f;
  M = M * (1.f - sp);
  R = R * rd + sp;
  T = tb + (T + ta*sp - tb) * 0.95f;
  sM[i] = M; sT[i] = T; sR[i] = R;
  return sp;
}
__device__ __forceinline__ void emit_spike(float sp, short* scat, size_t row, int off, int o,
                                           ull* pk, size_t i, int tid)
{
  scat[row*CATC + off + o] = (sp != 0.f) ? (short)0x3F80 : (short)0;
  ull ball = __ballot(sp != 0.f);
  if ((tid & 63) == 0) pk[i >> 6] = ball;
}

// ===================== kernels =====================
__global__ __launch_bounds__(256) void k_setup(
    const float* W1, const float* W2, const float* W3, const float* Wm,
    short* wcH1, short* wcH2, short* wcH3, short* WmH,
    double* S12all, double* aggD, unsigned* aggM, unsigned* cnt)
{
  int vb = blockIdx.x, tid = threadIdx.x;
  if (vb < 10){ for (int j=tid; j<1024; j+=256) stg_f64(S12all + (size_t)vb*1024 + j, 0.0); }
  else if (vb < 13){ int t = vb-10;
    for (int j=tid; j<1024; j+=256){ stg_f64(aggD + (size_t)t*1024 + j, 0.0); stg_u32(aggM + (size_t)t*1024 + j, 0u); } }
  else if (vb < 14){ if (tid < 16) stg_u32(cnt + tid, 0u); }
  else if (vb < 78)   wcatsplit(W1, wcH1, 128,  64, (size_t)(vb-14)*256 + tid);
  else if (vb < 334)  wcatsplit(W2, wcH2, 256, 128, (size_t)(vb-78)*256 + tid);
  else if (vb < 1358) wcatsplit(W3, wcH3, 512, 256, (size_t)(vb-334)*256 + tid);
  else                wsplit_store(Wm[(size_t)(vb-1358)*256 + tid], WmH, (size_t)512*960, (size_t)(vb-1358)*256 + tid);
}

__global__ __launch_bounds__(256) void k_nt0(const float* __restrict__ x, const float* __restrict__ W0,
                                             int* __restrict__ idx0, float* __restrict__ AB0)
{
  __shared__ __align__(16) float sm[6*64];
  int bid = blockIdx.x, tid = threadIdx.x;
  if (bid < 512) knn0_wave(x, idx0, bid*4 + (tid>>6), tid & 63);
  else           conv0_dev(x, W0, AB0, bid - 512, tid, sm);
}

// o-major gather: block = (rc, oc); lane owns column o = oc*64+lane across RPB rows.
__global__ __launch_bounds__(256) void k_gather2(const float* __restrict__ AB, const int* __restrict__ idx,
    float* __restrict__ hmaxS, double* __restrict__ S12, int O, int OC, int RPB)
{
  __shared__ double red[2][4][64];
  const int bid = blockIdx.x, tid = threadIdx.x;
  const int wave = tid >> 6, lane = tid & 63;
  const int oc = bid % OC, rc = bid / OC;
  const int o = oc*64 + lane;
  const int twoO = 2*O;
  const int rstart = rc * RPB;
  double ts1 = 0.0, ts2 = 0.0;
  for (int r = rstart + wave; r < rstart + RPB; r += 4){
    int b = r >> 10;
    const float* ABb = AB + (size_t)(b*NPTS)*twoO + o;
    float bc = AB[(size_t)r*twoO + O + o];
    const int* ip = idx + (size_t)r*IDXS;
    float mx = -INFINITY; double s1 = 0.0, s2 = 0.0;
#pragma unroll
    for (int k = 0; k < KNN; ++k){
      int m = ip[k];
      float a = ABb[(size_t)m*twoO];
      mx = fmaxf(mx, a); s1 += (double)a; s2 += (double)a*(double)a;
    }
    hmaxS[(size_t)r*O + o] = mx - bc;
    ts1 += s1 - (double)KNN*(double)bc;
    ts2 += s2 - 2.0*(double)bc*s1 + (double)KNN*(double)bc*(double)bc;
  }
  red[0][wave][lane] = ts1;
  red[1][wave][lane] = ts2;
  __syncthreads();
  if (wave == 0){
    double a = red[0][0][lane] + red[0][1][lane] + red[0][2][lane] + red[0][3][lane];
    double q = red[1][0][lane] + red[1][1][lane] + red[1][2][lane] + red[1][3][lane];
    atomicAdd(&S12[o], a);
    atomicAdd(&S12[512 + o], q);
  }
}

// lif0 (512 blocks) + 32x32 agg tiles of t-1 (1024 blocks when present)
__global__ __launch_bounds__(256) void k_lif0agg(const float* __restrict__ hmax0, const double* __restrict__ S12_0,
    const float* gv, const float* bv, const float* pmd, const float* pta, const float* prd, const float* ptb,
    float* sM, float* sT, float* sR, short* __restrict__ scat, ull* __restrict__ pk0, int init,
    const short* __restrict__ scatPrev, const short* __restrict__ WmH,
    double* __restrict__ aggDt, unsigned* __restrict__ aggMt)
{
  int bid = blockIdx.x, tid = threadIdx.x;
  if (bid < 512){
    int i = bid*256 + tid, o = i & 63;
    size_t row = (size_t)(i >> 6);
    float sp = lif_step(hmax0[i], o, (size_t)i, init, S12_0[o], S12_0[512+o],
                        gv, bv, pmd, pta, prd, ptb, sM, sT, sR);
    emit_spike(sp, scat, row, 0, o, pk0, (size_t)i, tid);
  } else {
    int tile = bid - 512;
    agg_tile32(scatPrev, WmH, aggDt, aggDt + 512, aggMt, tile >> 4, tile & 15, tid);
  }
}

template<int W>
__global__ __launch_bounds__(256) void k_knnconv(const ull* __restrict__ pk, int* __restrict__ idx,
    const short* __restrict__ Ain, const short* __restrict__ wcH,
    float* __restrict__ AB, int twoO, int K, int ntn)
{
  int bid = blockIdx.x, tid = threadIdx.x;
  if (bid < 512) knn_wave<W>(pk, idx, bid*4 + (tid>>6), tid & 63);
  else {
    int id = bid - 512, tm = id/ntn, tn = id - tm*ntn;
    mfma_dev(Ain, CATC, wcH, (size_t)twoO*K, K, AB, twoO, K, tm*64, tn*64, tid);
  }
}

// bnlif: streaming, one element per thread
__global__ __launch_bounds__(256) void k_bnlif(const float* __restrict__ hmaxS, int oShift,
    const double* __restrict__ S12,
    const float* gv, const float* bv, const float* pmd, const float* pta, const float* prd, const float* ptb,
    float* sM, float* sT, float* sR, short* __restrict__ scat, int offOut,
    ull* __restrict__ pkOut, int init)
{
  int i = blockIdx.x*256 + threadIdx.x;
  int O = 1 << oShift;
  int o = i & (O-1);
  size_t row = (size_t)(i >> oShift);
  float sp = lif_step(hmaxS[i], o, (size_t)i, init, S12[o], S12[512+o],
                      gv, bv, pmd, pta, prd, ptb, sM, sT, sR);
  emit_spike(sp, scat, row, offOut, o, pkOut, (size_t)i, threadIdx.x);
}

// 32x32 agg tiles of t=2 (1024 blocks) | one-directional counter wait | final (4 blocks)
__global__ __launch_bounds__(256) void k_aggfin(const short* __restrict__ scat2, const short* __restrict__ WmH,
    double* __restrict__ aggD, unsigned* __restrict__ aggM, unsigned* __restrict__ cnt,
    const float* gm, const float* bmv, const float* tw, const float* lftb, float* __restrict__ out)
{
  int bid = blockIdx.x, tid = threadIdx.x;
  if (bid < 1024){
    agg_tile32(scat2, WmH, aggD + 2048, aggD + 2048 + 512, aggM + 2048, bid >> 4, bid & 15, tid);
    asm volatile("s_waitcnt vmcnt(0)" ::: "memory");
    __syncthreads();
    if (tid == 0) __hip_atomic_fetch_add(cnt, 1u, __ATOMIC_RELAXED, __HIP_MEMORY_SCOPE_AGENT);
  } else {
    if (tid == 0) while (ldg_u32(cnt) < 1024u) __builtin_amdgcn_s_sleep(4);
    __syncthreads();
    int i = (bid - 1024)*256 + tid;
    int b = i >> 9, o = i & 511;
    float pool[3];
#pragma unroll
    for (int t = 0; t < 3; ++t){
      double s1v = ldg_f64(&aggD[(size_t)t*1024 + o]);
      double s2v = ldg_f64(&aggD[(size_t)t*1024 + 512 + o]);
      double mean = s1v / (double)ROWS;
      float var = (float)(s2v / (double)ROWS - mean*mean);
      float m = (float)mean;
      float inv = 1.f / sqrtf(var + 1e-5f);
      unsigned e = ldg_u32(&aggM[(size_t)t*1024 + b*512 + o]);
      unsigned u = (e & 0x80000000u) ? (e & 0x7FFFFFFFu) : ~e;
      float mx = __uint_as_float(u);
      pool[t] = lrelu_f(((mx - m)*inv)*gm[o] + bmv[o]);
    }
    float t0 = tw[0], t1 = tw[1], t2 = tw[2];
    float mxw = fmaxf(t0, fmaxf(t1, t2));
    float e0 = expf(t0-mxw), e1 = expf(t1-mxw), e2 = expf(t2-mxw);
    float den = e0 + e1 + e2;
    float v = (e0/den)*pool[0] + (e1/den)*pool[1] + (e2/den)*pool[2];
    out[i] = (v - lftb[o] > 0.f) ? 1.f : 0.f;
  }
}

// ===================== host =====================
extern "C" void kernel_launch(void* const* d_in, const int* in_sizes, int n_in,
                              void* d_out, int out_size, void* d_ws, size_t ws_size,
                              hipStream_t stream)
{
  (void)in_sizes; (void)n_in; (void)out_size; (void)ws_size;
  const float* x = (const float*)d_in[0];
  const float* Wl[4] = {(const float*)d_in[1],(const float*)d_in[4],(const float*)d_in[7],(const float*)d_in[10]};
  const float* gl[4] = {(const float*)d_in[2],(const float*)d_in[5],(const float*)d_in[8],(const float*)d_in[11]};
  const float* bl[4] = {(const float*)d_in[3],(const float*)d_in[6],(const float*)d_in[9],(const float*)d_in[12]};
  const float* Wm = (const float*)d_in[13];
  const float* gm = (const float*)d_in[14];
  const float* bm = (const float*)d_in[15];
  const float* lp[5][4];
  for (int l = 0; l < 5; ++l)
    for (int q = 0; q < 4; ++q)
      lp[l][q] = (const float*)d_in[16 + l*4 + q];
  const float* tw = (const float*)d_in[36];

  char* pw = (char*)d_ws;
  auto alloc = [&](size_t bytes)->char* {
    char* r = pw; pw += (bytes + 255) & ~(size_t)255; return r;
  };
  int*    idx0  = (int*)   alloc((size_t)ROWS*IDXS*sizeof(int));
  int*    idxS  = (int*)   alloc((size_t)ROWS*IDXS*sizeof(int));
  float*  AB0   = (float*) alloc((size_t)ROWS*128*sizeof(float));
  float*  AB    = (float*) alloc((size_t)ROWS*1024*sizeof(float));
  float*  hmax0 = (float*) alloc((size_t)ROWS*64*sizeof(float));
  float*  hmaxS = (float*) alloc((size_t)ROWS*512*sizeof(float));
  double* S12   = (double*)alloc((size_t)10*1024*sizeof(double));   // [0]=l0, [1+t*3+(li-1)]
  short*  scatH[3];
  for (int t = 0; t < 3; ++t) scatH[t] = (short*)alloc((size_t)ROWS*CATC*sizeof(short));
  int Wn[4] = {1, 2, 4, 8};
  ull* pk[4];
  for (int l = 0; l < 4; ++l) pk[l] = (ull*)alloc((size_t)ROWS*Wn[l]*sizeof(ull));
  double*   aggD = (double*)  alloc((size_t)3*1024*sizeof(double));
  unsigned* aggM = (unsigned*)alloc((size_t)3*1024*sizeof(unsigned));
  short* wcH[4];
  wcH[1] = (short*)alloc((size_t)3*2*128*64*sizeof(short));
  wcH[2] = (short*)alloc((size_t)3*2*256*128*sizeof(short));
  wcH[3] = (short*)alloc((size_t)3*2*512*256*sizeof(short));
  short* WmH = (short*)alloc((size_t)3*512*960*sizeof(short));
  int Oo[4] = {64, 128, 256, 512};
  float *stM[4], *stT[4], *stR[4];
  for (int l = 0; l < 4; ++l){
    stM[l] = (float*)alloc((size_t)ROWS*Oo[l]*sizeof(float));
    stT[l] = (float*)alloc((size_t)ROWS*Oo[l]*sizeof(float));
    stR[l] = (float*)alloc((size_t)ROWS*Oo[l]*sizeof(float));
  }
  unsigned* cnt = (unsigned*)alloc(256);

  k_setup<<<3278, 256, 0, stream>>>(Wl[1], Wl[2], Wl[3], Wm,
                                    wcH[1], wcH[2], wcH[3], WmH, S12, aggD, aggM, cnt);
  k_nt0<<<576, 256, 0, stream>>>(x, Wl[0], idx0, AB0);
  // gather0: O=64, OC=1, RC=512 -> RPB=4
  k_gather2<<<512, 256, 0, stream>>>(AB0, idx0, hmax0, S12, 64, 1, 4);

  int Cin[4]  = {3, 64, 128, 256};
  int offIn[4]= {0, 0, 64, 192};
  int offOut[4]={0, 64, 192, 448};

  for (int t = 0; t < TT; ++t){
    int init = (t == 0) ? 1 : 0;
    int grid0 = init ? 512 : (512 + 1024);
    k_lif0agg<<<grid0, 256, 0, stream>>>(hmax0, S12, gl[0], bl[0],
        lp[0][0], lp[0][1], lp[0][2], lp[0][3],
        stM[0], stT[0], stR[0], scatH[t], pk[0], init,
        init ? (const short*)nullptr : scatH[t-1], WmH,
        aggD + (size_t)(init ? 0 : (t-1))*1024, aggM + (size_t)(init ? 0 : (t-1))*1024);
    for (int li = 1; li < 4; ++li){
      int C = Cin[li], O = Oo[li], twoO = 2*O, ntn = twoO/64, nConv = 32*ntn;
      const short* fin = scatH[t] + offIn[li];
      double* S12i = S12 + (size_t)(1 + t*3 + (li-1))*1024;
      switch (Wn[li-1]){
        case 1: k_knnconv<1><<<512+nConv, 256, 0, stream>>>(pk[0], idxS, fin, wcH[li], AB, twoO, C, ntn); break;
        case 2: k_knnconv<2><<<512+nConv, 256, 0, stream>>>(pk[1], idxS, fin, wcH[li], AB, twoO, C, ntn); break;
        default: k_knnconv<4><<<512+nConv, 256, 0, stream>>>(pk[2], idxS, fin, wcH[li], AB, twoO, C, ntn); break;
      }
      // o-major gather: OC = O/64, RC = 512/OC, RPB = 2048/RC = 4*OC
      int OC = O/64;
      k_gather2<<<512, 256, 0, stream>>>(AB, idxS, hmaxS, S12i, O, OC, 4*OC);
      int oSh = (O==128)?7:(O==256)?8:9;
      k_bnlif<<<(ROWS*O)/256, 256, 0, stream>>>(hmaxS, oSh, S12i,
          gl[li], bl[li], lp[li][0], lp[li][1], lp[li][2], lp[li][3],
          stM[li], stT[li], stR[li], scatH[t], offOut[li], pk[li], init);
    }
  }
  k_aggfin<<<1028, 256, 0, stream>>>(scatH[2], WmH, aggD, aggM, cnt + 9,
                                     gm, bm, tw, lp[4][3], (float*)d_out);
}

// Round 13
// 435.028 us; speedup vs baseline: 1.2274x; 1.2274x over previous
//
#include <hip/hip_runtime.h>
#include <math.h>

#define NPTS 1024
#define BB 2
#define KNN 20
#define ROWS 2048
#define CATC 960
#define TT 3
#define IDXS 32
typedef unsigned long long ull;
typedef __attribute__((ext_vector_type(8))) short bf16x8;
typedef __attribute__((ext_vector_type(4))) float f32x4;

__device__ __forceinline__ float lrelu_f(float x){ return x >= 0.f ? x : 0.2f*x; }
__device__ __forceinline__ unsigned short f2bf(float f){
  unsigned u = __float_as_uint(f);
  return (unsigned short)((u + 0x7FFFu + ((u >> 16) & 1u)) >> 16);
}
__device__ __forceinline__ float bf2f(unsigned short h){ return __uint_as_float(((unsigned)h) << 16); }

__device__ __forceinline__ void stg_u32(unsigned* p, unsigned v){ __hip_atomic_store(p, v, __ATOMIC_RELAXED, __HIP_MEMORY_SCOPE_AGENT); }
__device__ __forceinline__ void stg_f64(double* p, double v){ __hip_atomic_store(p, v, __ATOMIC_RELAXED, __HIP_MEMORY_SCOPE_AGENT); }
__device__ __forceinline__ unsigned ldg_u32(const unsigned* p){ return __hip_atomic_load(p, __ATOMIC_RELAXED, __HIP_MEMORY_SCOPE_AGENT); }
__device__ __forceinline__ double ldg_f64(const double* p){ return __hip_atomic_load(p, __ATOMIC_RELAXED, __HIP_MEMORY_SCOPE_AGENT); }

// ===================== MFMA bf16 3-split conv GEMM (LDS-free, 64x64 tile) =====================
__device__ __forceinline__ void mfma_dev(const short* __restrict__ A, int lda,
    const short* __restrict__ B3, size_t sStride, int ldb,
    float* __restrict__ C, int ldc, int K, int bm, int bn, int tid)
{
  const int wave = tid >> 6, lane = tid & 63;
  const int wm = (wave >> 1) << 5, wn = (wave & 1) << 5;
  const int rr = lane & 15, kq = (lane >> 4) << 3;
  f32x4 acc[2][2] = {};
  const short* Ap = A + (size_t)(bm + wm + rr)*lda + kq;
  const short* Bp = B3 + (size_t)(bn + wn + rr)*ldb + kq;
  for (int k0 = 0; k0 < K; k0 += 32) {
    bf16x8 a0 = *(const bf16x8*)(Ap + k0);
    bf16x8 a1 = *(const bf16x8*)(Ap + (size_t)16*lda + k0);
#pragma unroll
    for (int s = 0; s < 3; ++s) {
      bf16x8 b0 = *(const bf16x8*)(Bp + (size_t)s*sStride + k0);
      bf16x8 b1 = *(const bf16x8*)(Bp + (size_t)s*sStride + (size_t)16*ldb + k0);
      acc[0][0] = __builtin_amdgcn_mfma_f32_16x16x32_bf16(a0, b0, acc[0][0], 0, 0, 0);
      acc[0][1] = __builtin_amdgcn_mfma_f32_16x16x32_bf16(a0, b1, acc[0][1], 0, 0, 0);
      acc[1][0] = __builtin_amdgcn_mfma_f32_16x16x32_bf16(a1, b0, acc[1][0], 0, 0, 0);
      acc[1][1] = __builtin_amdgcn_mfma_f32_16x16x32_bf16(a1, b1, acc[1][1], 0, 0, 0);
    }
  }
  const int drb = (lane >> 4) << 2;
#pragma unroll
  for (int i = 0; i < 2; ++i)
#pragma unroll
    for (int j = 0; j < 2; ++j)
#pragma unroll
      for (int t = 0; t < 4; ++t)
        C[(size_t)(bm + wm + i*16 + drb + t)*ldc + bn + wn + j*16 + rr] = acc[i][j][t];
}

// ===================== agg MFMA 64x64 tile (256 blocks): 4 acc chains/wave, fused stats =====================
__device__ __forceinline__ void agg_tile64(const short* __restrict__ scat, const short* __restrict__ WmH,
    double* __restrict__ Sa1, double* __restrict__ Sa2, unsigned* __restrict__ mxe,
    int tm, int tn, int tid)
{
  const int wave = tid >> 6, lane = tid & 63;
  const int wm = (wave >> 1) << 5;   // 0/32
  const int wn = (wave & 1) << 5;    // 0/32
  const int rr = lane & 15, kq = (lane >> 4) << 3;
  const int bm = tm*64, bn = tn*64;
  f32x4 acc[2][2] = {};
  const short* Ap = scat + (size_t)(bm + wm + rr)*CATC + kq;
  const short* Bp = WmH + (size_t)(bn + wn + rr)*960 + kq;
  for (int k0 = 0; k0 < 960; k0 += 32){
    bf16x8 a0 = *(const bf16x8*)(Ap + k0);
    bf16x8 a1 = *(const bf16x8*)(Ap + (size_t)16*CATC + k0);
#pragma unroll
    for (int s = 0; s < 3; ++s){
      bf16x8 b0 = *(const bf16x8*)(Bp + (size_t)s*491520 + k0);
      bf16x8 b1 = *(const bf16x8*)(Bp + (size_t)s*491520 + (size_t)16*960 + k0);
      acc[0][0] = __builtin_amdgcn_mfma_f32_16x16x32_bf16(a0, b0, acc[0][0], 0, 0, 0);
      acc[0][1] = __builtin_amdgcn_mfma_f32_16x16x32_bf16(a0, b1, acc[0][1], 0, 0, 0);
      acc[1][0] = __builtin_amdgcn_mfma_f32_16x16x32_bf16(a1, b0, acc[1][0], 0, 0, 0);
      acc[1][1] = __builtin_amdgcn_mfma_f32_16x16x32_bf16(a1, b1, acc[1][1], 0, 0, 0);
    }
  }
#pragma unroll
  for (int j = 0; j < 2; ++j){
    double ds = 0.0, dq = 0.0; float mx = -INFINITY;
#pragma unroll
    for (int i = 0; i < 2; ++i)
#pragma unroll
      for (int t = 0; t < 4; ++t){
        float v = acc[i][j][t];
        ds += (double)v; dq += (double)v*(double)v; mx = fmaxf(mx, v);
      }
#pragma unroll
    for (int off = 16; off < 64; off <<= 1){
      ds += __shfl_xor(ds, off);
      dq += __shfl_xor(dq, off);
      float o = __shfl_xor(mx, off); mx = fmaxf(mx, o);
    }
    if (lane < 16){
      int col = bn + wn + j*16 + lane;
      atomicAdd(&Sa1[col], ds);
      atomicAdd(&Sa2[col], dq);
      unsigned u = __float_as_uint(mx);
      u = (u & 0x80000000u) ? ~u : (u | 0x80000000u);
      atomicMax(&mxe[(bm >> 10)*512 + col], u);
    }
  }
}

// ===================== wave-level popcount KNN =====================
template<int W>
__device__ __forceinline__ void knn_wave(const ull* __restrict__ pk, int* __restrict__ idx,
                                         int row, int lane)
{
  const int n = row & (NPTS-1), b = row >> 10;
  const ull* pb = pk + (size_t)b*NPTS*W;
  ull cw[W]; int pn = 0;
#pragma unroll
  for (int w=0; w<W; ++w){ cw[w] = pb[(size_t)n*W + w]; pn += __popcll(cw[w]); }
  unsigned keys[16];
#pragma unroll 4
  for (int i=0;i<16;++i){
    int m = lane + (i<<6);
    int inner=0, pm=0;
#pragma unroll
    for (int w=0;w<W;++w){
      ull rm = pb[(size_t)m*W + w];
      inner += __popcll(rm & cw[w]);
      pm    += __popcll(rm);
    }
    int d = 2*inner - pn - pm;
    keys[i] = ((unsigned)(d+1024)<<11) | (unsigned)(NPTS-1-m);
  }
  unsigned lmax = keys[0];
#pragma unroll
  for (int i=1;i<16;++i) lmax = keys[i]>lmax ? keys[i] : lmax;
  unsigned mywin = 0;
  for (int s=0;s<KNN;++s){
    unsigned v = lmax;
#pragma unroll
    for (int off=1; off<64; off<<=1){ unsigned o = __shfl_xor(v, off, 64); if (o>v) v=o; }
    if (lane == s) mywin = (unsigned)(NPTS-1) - (v & 0x7FFu);
    if (lmax == v){
#pragma unroll
      for (int i=0;i<16;++i) if (keys[i]==v) keys[i]=0u;
      lmax = keys[0];
#pragma unroll
      for (int i=1;i<16;++i) lmax = keys[i]>lmax ? keys[i] : lmax;
    }
  }
  if (lane < KNN) idx[(size_t)row*IDXS + lane] = (int)mywin;
}

// ===================== layer-0 KNN (fp32, exact ref op order) =====================
__device__ __forceinline__ void knn0_wave(const float* __restrict__ x, int* __restrict__ idx,
                                          int row, int lane)
{
  const int n = row & (NPTS-1), b = row >> 10;
  const float* xb = x + (size_t)b*3*NPTS;
  float fn0 = xb[n], fn1 = xb[NPTS+n], fn2 = xb[2*NPTS+n];
  float x2n = __fadd_rn(__fadd_rn(__fmul_rn(fn0,fn0), __fmul_rn(fn1,fn1)), __fmul_rn(fn2,fn2));
  ull keys[16];
#pragma unroll 4
  for (int i=0;i<16;++i){
    int m = lane + (i<<6);
    float a0 = xb[m], a1 = xb[NPTS+m], a2 = xb[2*NPTS+m];
    float x2m = __fadd_rn(__fadd_rn(__fmul_rn(a0,a0), __fmul_rn(a1,a1)), __fmul_rn(a2,a2));
    float inner = __fadd_rn(__fadd_rn(__fmul_rn(fn0,a0), __fmul_rn(fn1,a1)), __fmul_rn(fn2,a2));
    float v = __fsub_rn(__fsub_rn(__fmul_rn(2.f,inner), x2n), x2m);
    unsigned u = __float_as_uint(v);
    u = (u & 0x80000000u) ? ~u : (u | 0x80000000u);
    keys[i] = ((ull)u << 32) | (unsigned)(NPTS-1-m);
  }
  ull lmax = keys[0];
#pragma unroll
  for (int i=1;i<16;++i) lmax = keys[i]>lmax ? keys[i] : lmax;
  unsigned mywin = 0;
  for (int s=0;s<KNN;++s){
    ull v = lmax;
#pragma unroll
    for (int off=1; off<64; off<<=1){ ull o = __shfl_xor(v, off, 64); if (o>v) v=o; }
    if (lane == s) mywin = (unsigned)(NPTS-1) - (unsigned)(v & 0xFFFFFFFFull);
    if (lmax == v){
#pragma unroll
      for (int i=0;i<16;++i) if (keys[i]==v) keys[i]=0ull;
      lmax = keys[0];
#pragma unroll
      for (int i=1;i<16;++i) lmax = keys[i]>lmax ? keys[i] : lmax;
    }
  }
  if (lane < KNN) idx[(size_t)row*IDXS + lane] = (int)mywin;
}

// ===================== conv0 (K=3, fp32) =====================
__device__ __forceinline__ void conv0_dev(const float* __restrict__ x, const float* __restrict__ W0,
    float* __restrict__ AB0, int tile, int tid, float* sm)
{
  float (*As)[64] = (float(*)[64])sm;
  float (*Bs)[64] = (float(*)[64])(sm + 3*64);
  int bm = (tile >> 1) * 64, bn = (tile & 1) * 64;
  int b = bm >> 10, n0 = bm & (NPTS-1);
  if (tid < 192){ int k = tid >> 6, r = tid & 63; As[k][r] = x[(size_t)b*3072 + k*NPTS + n0 + r]; }
  if (tid >= 64){
    int k = (tid - 64) >> 6, c = (tid - 64) & 63; int row = bn + c;
    Bs[k][c] = (row < 64) ? __fadd_rn(W0[(size_t)row*6+k], W0[(size_t)row*6+3+k])
                          : W0[(size_t)(row-64)*6+k];
  }
  __syncthreads();
  const int tx = tid & 15, ty = tid >> 4;
  float acc[4][4] = {};
#pragma unroll
  for (int kk = 0; kk < 3; ++kk){
    float ar[4], br[4];
#pragma unroll
    for (int i=0;i<4;++i) ar[i] = As[kk][ty*4+i];
#pragma unroll
    for (int j=0;j<4;++j) br[j] = Bs[kk][tx*4+j];
#pragma unroll
    for (int i=0;i<4;++i)
#pragma unroll
      for (int j=0;j<4;++j) acc[i][j] = fmaf(ar[i], br[j], acc[i][j]);
  }
#pragma unroll
  for (int i=0;i<4;++i)
#pragma unroll
    for (int j=0;j<4;++j)
      AB0[(size_t)(bm+ty*4+i)*128 + bn+tx*4+j] = acc[i][j];
  __syncthreads();
}

// ===================== weight split (3x bf16) =====================
__device__ __forceinline__ void wsplit_store(float w, short* dst, size_t NK, size_t e){
  unsigned short h1 = f2bf(w); float f1 = bf2f(h1);
  float r1 = w - f1;
  unsigned short h2 = f2bf(r1); float f2v = bf2f(h2);
  unsigned short h3 = f2bf(r1 - f2v);
  dst[e] = (short)h1; dst[NK + e] = (short)h2; dst[2*NK + e] = (short)h3;
}
__device__ __forceinline__ void wcatsplit(const float* __restrict__ W, short* __restrict__ dst,
                                          int O, int C, size_t e){
  int rr = (int)(e / C), cc = (int)(e - (size_t)rr*C);
  float w = (rr < O) ? __fadd_rn(W[(size_t)rr*2*C + cc], W[(size_t)rr*2*C + C + cc])
                     : W[(size_t)(rr-O)*2*C + cc];
  wsplit_store(w, dst, (size_t)2*O*C, e);
}

// ===================== LIF =====================
__device__ __forceinline__ float lif_step(float h, int o, size_t i, int init,
    double s1v, double s2v,
    const float* gv, const float* bv,
    const float* pmd, const float* pta, const float* prd, const float* ptb,
    float* sM, float* sT, float* sR)
{
  double cnt = (double)ROWS * (double)KNN;
  double mu = s1v / cnt;
  double vv = s2v / cnt - mu*mu;
  float mean = (float)mu;
  float inv  = 1.f / sqrtf((float)vv + 1e-5f);
  h = ((h - mean) * inv) * gv[o] + bv[o];
  h = lrelu_f(h);
  float md = fminf(fmaxf(pmd[o], 0.1f), 0.99f);
  float ta = fminf(fmaxf(pta[o], 0.001f), 0.1f);
  float rd = fminf(fmaxf(prd[o], 0.1f), 0.95f);
  float tb = ptb[o];
  float M, T, R;
  if (init) { M = 0.f; T = tb; R = 0.f; }
  else      { M = sM[i]; T = sT[i]; R = sR[i]; }
  float xv = (R <= 0.f) ? h : 0.f;
  M = M * md * (1.f - R) + xv;
  float sp = (M - T > 0.f) ? 1.f : 0.f;
  M = M * (1.f - sp);
  R = R * rd + sp;
  T = tb + (T + ta*sp - tb) * 0.95f;
  sM[i] = M; sT[i] = T; sR[i] = R;
  return sp;
}
__device__ __forceinline__ void emit_spike(float sp, short* scat, size_t row, int off, int o,
                                           ull* pk, size_t i, int tid)
{
  scat[row*CATC + off + o] = (sp != 0.f) ? (short)0x3F80 : (short)0;
  ull ball = __ballot(sp != 0.f);
  if ((tid & 63) == 0) pk[i >> 6] = ball;
}

// ===================== kernels =====================
__global__ __launch_bounds__(256) void k_setup(
    const float* W1, const float* W2, const float* W3, const float* Wm,
    short* wcH1, short* wcH2, short* wcH3, short* WmH,
    double* S12all, double* aggD, unsigned* aggM, unsigned* cnt)
{
  int vb = blockIdx.x, tid = threadIdx.x;
  if (vb < 10){ for (int j=tid; j<1024; j+=256) stg_f64(S12all + (size_t)vb*1024 + j, 0.0); }
  else if (vb < 13){ int t = vb-10;
    for (int j=tid; j<1024; j+=256){ stg_f64(aggD + (size_t)t*1024 + j, 0.0); stg_u32(aggM + (size_t)t*1024 + j, 0u); } }
  else if (vb < 14){ if (tid < 16) stg_u32(cnt + tid, 0u); }
  else if (vb < 78)   wcatsplit(W1, wcH1, 128,  64, (size_t)(vb-14)*256 + tid);
  else if (vb < 334)  wcatsplit(W2, wcH2, 256, 128, (size_t)(vb-78)*256 + tid);
  else if (vb < 1358) wcatsplit(W3, wcH3, 512, 256, (size_t)(vb-334)*256 + tid);
  else                wsplit_store(Wm[(size_t)(vb-1358)*256 + tid], WmH, (size_t)512*960, (size_t)(vb-1358)*256 + tid);
}

__global__ __launch_bounds__(256) void k_nt0(const float* __restrict__ x, const float* __restrict__ W0,
                                             int* __restrict__ idx0, float* __restrict__ AB0)
{
  __shared__ __align__(16) float sm[6*64];
  int bid = blockIdx.x, tid = threadIdx.x;
  if (bid < 512) knn0_wave(x, idx0, bid*4 + (tid>>6), tid & 63);
  else           conv0_dev(x, W0, AB0, bid - 512, tid, sm);
}

// o-major gather: block = (rc, oc); lane owns column o = oc*64+lane across RPB rows.
__global__ __launch_bounds__(256) void k_gather2(const float* __restrict__ AB, const int* __restrict__ idx,
    float* __restrict__ hmaxS, double* __restrict__ S12, int O, int OC, int RPB)
{
  __shared__ double red[2][4][64];
  const int bid = blockIdx.x, tid = threadIdx.x;
  const int wave = tid >> 6, lane = tid & 63;
  const int oc = bid % OC, rc = bid / OC;
  const int o = oc*64 + lane;
  const int twoO = 2*O;
  const int rstart = rc * RPB;
  double ts1 = 0.0, ts2 = 0.0;
  for (int r = rstart + wave; r < rstart + RPB; r += 4){
    int b = r >> 10;
    const float* ABb = AB + (size_t)(b*NPTS)*twoO + o;
    float bc = AB[(size_t)r*twoO + O + o];
    const int* ip = idx + (size_t)r*IDXS;
    float mx = -INFINITY; double s1 = 0.0, s2 = 0.0;
#pragma unroll
    for (int k = 0; k < KNN; ++k){
      int m = ip[k];
      float a = ABb[(size_t)m*twoO];
      mx = fmaxf(mx, a); s1 += (double)a; s2 += (double)a*(double)a;
    }
    hmaxS[(size_t)r*O + o] = mx - bc;
    ts1 += s1 - (double)KNN*(double)bc;
    ts2 += s2 - 2.0*(double)bc*s1 + (double)KNN*(double)bc*(double)bc;
  }
  red[0][wave][lane] = ts1;
  red[1][wave][lane] = ts2;
  __syncthreads();
  if (wave == 0){
    double a = red[0][0][lane] + red[0][1][lane] + red[0][2][lane] + red[0][3][lane];
    double q = red[1][0][lane] + red[1][1][lane] + red[1][2][lane] + red[1][3][lane];
    atomicAdd(&S12[o], a);
    atomicAdd(&S12[512 + o], q);
  }
}

// standalone lif0 (t=0 only)
__global__ __launch_bounds__(256) void k_lif0(const float* __restrict__ hmax0, const double* __restrict__ S12_0,
    const float* gv, const float* bv, const float* pmd, const float* pta, const float* prd, const float* ptb,
    float* sM, float* sT, float* sR, short* __restrict__ scat, ull* __restrict__ pk0)
{
  int i = blockIdx.x*256 + threadIdx.x, o = i & 63;
  size_t row = (size_t)(i >> 6);
  float sp = lif_step(hmax0[i], o, (size_t)i, 1, S12_0[o], S12_0[512+o],
                      gv, bv, pmd, pta, prd, ptb, sM, sT, sR);
  emit_spike(sp, scat, row, 0, o, pk0, (size_t)i, threadIdx.x);
}

// knn (512) + conv tiles + optional agg(t-1) 64x64 tiles appended
template<int W>
__global__ __launch_bounds__(256) void k_knnconv(const ull* __restrict__ pk, int* __restrict__ idx,
    const short* __restrict__ Ain, const short* __restrict__ wcH,
    float* __restrict__ AB, int twoO, int K, int ntn,
    const short* __restrict__ scatPrev, const short* __restrict__ WmH,
    double* __restrict__ aggDt, unsigned* __restrict__ aggMt, int nMain)
{
  int bid = blockIdx.x, tid = threadIdx.x;
  if (bid < 512) knn_wave<W>(pk, idx, bid*4 + (tid>>6), tid & 63);
  else if (bid < nMain){
    int id = bid - 512, tm = id/ntn, tn = id - tm*ntn;
    mfma_dev(Ain, CATC, wcH, (size_t)twoO*K, K, AB, twoO, K, tm*64, tn*64, tid);
  } else {
    int tile = bid - nMain;
    agg_tile64(scatPrev, WmH, aggDt, aggDt + 512, aggMt, tile >> 3, tile & 7, tid);
  }
}

// bnlif streaming + optional lif0(t+1) tail blocks
__global__ __launch_bounds__(256) void k_bnlif(const float* __restrict__ hmaxS, int oShift,
    const double* __restrict__ S12,
    const float* gv, const float* bv, const float* pmd, const float* pta, const float* prd, const float* ptb,
    float* sM, float* sT, float* sR, short* __restrict__ scat, int offOut,
    ull* __restrict__ pkOut, int init, int nMain,
    const float* __restrict__ hmax0, const double* __restrict__ S12_0,
    const float* g0, const float* b0, const float* pmd0, const float* pta0, const float* prd0, const float* ptb0,
    float* sM0, float* sT0, float* sR0, short* __restrict__ scatN, ull* __restrict__ pk0)
{
  int bid = blockIdx.x, tid = threadIdx.x;
  if (bid < nMain){
    int i = bid*256 + tid;
    int O = 1 << oShift;
    int o = i & (O-1);
    size_t row = (size_t)(i >> oShift);
    float sp = lif_step(hmaxS[i], o, (size_t)i, init, S12[o], S12[512+o],
                        gv, bv, pmd, pta, prd, ptb, sM, sT, sR);
    emit_spike(sp, scat, row, offOut, o, pkOut, (size_t)i, tid);
  } else {
    int i = (bid - nMain)*256 + tid, o = i & 63;
    size_t row = (size_t)(i >> 6);
    float sp = lif_step(hmax0[i], o, (size_t)i, 0, S12_0[o], S12_0[512+o],
                        g0, b0, pmd0, pta0, prd0, ptb0, sM0, sT0, sR0);
    emit_spike(sp, scatN, row, 0, o, pk0, (size_t)i, tid);
  }
}

// agg(t=2) 256 tiles | counter wait | final (4 blocks)
__global__ __launch_bounds__(256) void k_aggfin(const short* __restrict__ scat2, const short* __restrict__ WmH,
    double* __restrict__ aggD, unsigned* __restrict__ aggM, unsigned* __restrict__ cnt,
    const float* gm, const float* bmv, const float* tw, const float* lftb, float* __restrict__ out)
{
  int bid = blockIdx.x, tid = threadIdx.x;
  if (bid < 256){
    agg_tile64(scat2, WmH, aggD + 2048, aggD + 2048 + 512, aggM + 2048, bid >> 3, bid & 7, tid);
    asm volatile("s_waitcnt vmcnt(0)" ::: "memory");
    __syncthreads();
    if (tid == 0) __hip_atomic_fetch_add(cnt, 1u, __ATOMIC_RELAXED, __HIP_MEMORY_SCOPE_AGENT);
  } else {
    if (tid == 0) while (ldg_u32(cnt) < 256u) __builtin_amdgcn_s_sleep(4);
    __syncthreads();
    int i = (bid - 256)*256 + tid;
    int b = i >> 9, o = i & 511;
    float pool[3];
#pragma unroll
    for (int t = 0; t < 3; ++t){
      double s1v = ldg_f64(&aggD[(size_t)t*1024 + o]);
      double s2v = ldg_f64(&aggD[(size_t)t*1024 + 512 + o]);
      double mean = s1v / (double)ROWS;
      float var = (float)(s2v / (double)ROWS - mean*mean);
      float m = (float)mean;
      float inv = 1.f / sqrtf(var + 1e-5f);
      unsigned e = ldg_u32(&aggM[(size_t)t*1024 + b*512 + o]);
      unsigned u = (e & 0x80000000u) ? (e & 0x7FFFFFFFu) : ~e;
      float mx = __uint_as_float(u);
      pool[t] = lrelu_f(((mx - m)*inv)*gm[o] + bmv[o]);
    }
    float t0 = tw[0], t1 = tw[1], t2 = tw[2];
    float mxw = fmaxf(t0, fmaxf(t1, t2));
    float e0 = expf(t0-mxw), e1 = expf(t1-mxw), e2 = expf(t2-mxw);
    float den = e0 + e1 + e2;
    float v = (e0/den)*pool[0] + (e1/den)*pool[1] + (e2/den)*pool[2];
    out[i] = (v - lftb[o] > 0.f) ? 1.f : 0.f;
  }
}

// ===================== host =====================
extern "C" void kernel_launch(void* const* d_in, const int* in_sizes, int n_in,
                              void* d_out, int out_size, void* d_ws, size_t ws_size,
                              hipStream_t stream)
{
  (void)in_sizes; (void)n_in; (void)out_size; (void)ws_size;
  const float* x = (const float*)d_in[0];
  const float* Wl[4] = {(const float*)d_in[1],(const float*)d_in[4],(const float*)d_in[7],(const float*)d_in[10]};
  const float* gl[4] = {(const float*)d_in[2],(const float*)d_in[5],(const float*)d_in[8],(const float*)d_in[11]};
  const float* bl[4] = {(const float*)d_in[3],(const float*)d_in[6],(const float*)d_in[9],(const float*)d_in[12]};
  const float* Wm = (const float*)d_in[13];
  const float* gm = (const float*)d_in[14];
  const float* bm = (const float*)d_in[15];
  const float* lp[5][4];
  for (int l = 0; l < 5; ++l)
    for (int q = 0; q < 4; ++q)
      lp[l][q] = (const float*)d_in[16 + l*4 + q];
  const float* tw = (const float*)d_in[36];

  char* pw = (char*)d_ws;
  auto alloc = [&](size_t bytes)->char* {
    char* r = pw; pw += (bytes + 255) & ~(size_t)255; return r;
  };
  int*    idx0  = (int*)   alloc((size_t)ROWS*IDXS*sizeof(int));
  int*    idxS  = (int*)   alloc((size_t)ROWS*IDXS*sizeof(int));
  float*  AB0   = (float*) alloc((size_t)ROWS*128*sizeof(float));
  float*  AB    = (float*) alloc((size_t)ROWS*1024*sizeof(float));
  float*  hmax0 = (float*) alloc((size_t)ROWS*64*sizeof(float));
  float*  hmaxS = (float*) alloc((size_t)ROWS*512*sizeof(float));
  double* S12   = (double*)alloc((size_t)10*1024*sizeof(double));   // [0]=l0, [1+t*3+(li-1)]
  short*  scatH[3];
  for (int t = 0; t < 3; ++t) scatH[t] = (short*)alloc((size_t)ROWS*CATC*sizeof(short));
  int Wn[4] = {1, 2, 4, 8};
  ull* pk[4];
  for (int l = 0; l < 4; ++l) pk[l] = (ull*)alloc((size_t)ROWS*Wn[l]*sizeof(ull));
  double*   aggD = (double*)  alloc((size_t)3*1024*sizeof(double));
  unsigned* aggM = (unsigned*)alloc((size_t)3*1024*sizeof(unsigned));
  short* wcH[4];
  wcH[1] = (short*)alloc((size_t)3*2*128*64*sizeof(short));
  wcH[2] = (short*)alloc((size_t)3*2*256*128*sizeof(short));
  wcH[3] = (short*)alloc((size_t)3*2*512*256*sizeof(short));
  short* WmH = (short*)alloc((size_t)3*512*960*sizeof(short));
  int Oo[4] = {64, 128, 256, 512};
  float *stM[4], *stT[4], *stR[4];
  for (int l = 0; l < 4; ++l){
    stM[l] = (float*)alloc((size_t)ROWS*Oo[l]*sizeof(float));
    stT[l] = (float*)alloc((size_t)ROWS*Oo[l]*sizeof(float));
    stR[l] = (float*)alloc((size_t)ROWS*Oo[l]*sizeof(float));
  }
  unsigned* cnt = (unsigned*)alloc(256);

  k_setup<<<3278, 256, 0, stream>>>(Wl[1], Wl[2], Wl[3], Wm,
                                    wcH[1], wcH[2], wcH[3], WmH, S12, aggD, aggM, cnt);
  k_nt0<<<576, 256, 0, stream>>>(x, Wl[0], idx0, AB0);
  k_gather2<<<512, 256, 0, stream>>>(AB0, idx0, hmax0, S12, 64, 1, 4);
  k_lif0<<<512, 256, 0, stream>>>(hmax0, S12, gl[0], bl[0],
      lp[0][0], lp[0][1], lp[0][2], lp[0][3],
      stM[0], stT[0], stR[0], scatH[0], pk[0]);

  int Cin[4]  = {3, 64, 128, 256};
  int offIn[4]= {0, 0, 64, 192};
  int offOut[4]={0, 64, 192, 448};

  for (int t = 0; t < TT; ++t){
    int init = (t == 0) ? 1 : 0;
    for (int li = 1; li < 4; ++li){
      int C = Cin[li], O = Oo[li], twoO = 2*O, ntn = twoO/64, nConv = 32*ntn;
      const short* fin = scatH[t] + offIn[li];
      double* S12i = S12 + (size_t)(1 + t*3 + (li-1))*1024;
      int nMain2 = 512 + nConv;
      int hasAgg = (li == 1 && t > 0) ? 1 : 0;
      int gridK = nMain2 + (hasAgg ? 256 : 0);
      const short* scPrev = hasAgg ? scatH[t-1] : (const short*)nullptr;
      double* aggDt = aggD + (size_t)(hasAgg ? (t-1) : 0)*1024;
      unsigned* aggMt = aggM + (size_t)(hasAgg ? (t-1) : 0)*1024;
      switch (Wn[li-1]){
        case 1: k_knnconv<1><<<gridK, 256, 0, stream>>>(pk[0], idxS, fin, wcH[li], AB, twoO, C, ntn,
                    scPrev, WmH, aggDt, aggMt, nMain2); break;
        case 2: k_knnconv<2><<<gridK, 256, 0, stream>>>(pk[1], idxS, fin, wcH[li], AB, twoO, C, ntn,
                    scPrev, WmH, aggDt, aggMt, nMain2); break;
        default: k_knnconv<4><<<gridK, 256, 0, stream>>>(pk[2], idxS, fin, wcH[li], AB, twoO, C, ntn,
                    scPrev, WmH, aggDt, aggMt, nMain2); break;
      }
      int OC = O/64;
      k_gather2<<<512, 256, 0, stream>>>(AB, idxS, hmaxS, S12i, O, OC, 4*OC);
      int oSh = (O==128)?7:(O==256)?8:9;
      int nMainB = (ROWS*O)/256;
      int tailLif0 = (li == 3 && t < 2) ? 512 : 0;
      k_bnlif<<<nMainB + tailLif0, 256, 0, stream>>>(hmaxS, oSh, S12i,
          gl[li], bl[li], lp[li][0], lp[li][1], lp[li][2], lp[li][3],
          stM[li], stT[li], stR[li], scatH[t], offOut[li], pk[li], init, nMainB,
          hmax0, S12, gl[0], bl[0], lp[0][0], lp[0][1], lp[0][2], lp[0][3],
          stM[0], stT[0], stR[0], (t < 2) ? scatH[t+1] : (short*)nullptr, pk[0]);
    }
  }
  k_aggfin<<<260, 256, 0, stream>>>(scatH[2], WmH, aggD, aggM, cnt + 9,
                                    gm, bm, tw, lp[4][3], (float*)d_out);
}